// Round 1
// baseline (341.038 us; speedup 1.0000x reference)
//
#include <hip/hip_runtime.h>
#include <hip/hip_bf16.h>
#include <stdint.h>

#define B_ 4
#define T_ 2048
#define D_ 1024
#define H_ 16
#define DK_ 64
#define M_ (B_*T_)   // 8192

typedef __attribute__((ext_vector_type(8))) short bf16x8;
typedef __attribute__((ext_vector_type(4))) float f32x4;
typedef __hip_bfloat16 bf16;

// ---------------------------------------------------------------------------
// async global->LDS, 16B per lane. LDS dest is wave-uniform base + lane*16;
// we pass each lane's own linear pointer (lane0's value is the wave base).
// ---------------------------------------------------------------------------
__device__ __forceinline__ void gld_lds16(const bf16* g, bf16* l) {
  __builtin_amdgcn_global_load_lds((const __attribute__((address_space(1))) void*)g,
                                   (__attribute__((address_space(3))) void*)l,
                                   16, 0, 0);
}

// ---------------------------------------------------------------------------
// fp32 -> bf16 elementwise convert (vectorized: float4 in, 4x bf16 out)
// ---------------------------------------------------------------------------
__global__ __launch_bounds__(256) void cvt_bf16(const float* __restrict__ in,
                                                bf16* __restrict__ out, int n4) {
  int i = blockIdx.x * 256 + threadIdx.x;
  if (i < n4) {
    float4 v = reinterpret_cast<const float4*>(in)[i];
    union { ushort4 u; bf16 h[4]; } o;
    o.h[0] = __float2bfloat16(v.x);
    o.h[1] = __float2bfloat16(v.y);
    o.h[2] = __float2bfloat16(v.z);
    o.h[3] = __float2bfloat16(v.w);
    reinterpret_cast<ushort4*>(out)[i] = o.u;
  }
}

// ---------------------------------------------------------------------------
// NT GEMM: A[M][K] (k-contig) * B[N][K]^T (k-contig), K=1024 fixed.
// 128x128 tile, BK=64, 256 threads = 4 waves in 2x2, each wave 64x64 out.
// LDS XOR-swizzle (slot ^= row&7, 8 x 16B slots per 64-elem row) with the
// inverse swizzle applied to the global_load_lds SOURCE address (rule #21).
// Epilogue modes:
//   CM_QK : bf16 out, (B,H,T,DK) permuted layout, (acc+bias)*scale
//   CM_VT : bf16 out, operands swapped (A=W, B=x): out (B,H,DK,T), bias[row]
//   CM_OUT: fp32 out, row-major (M,N), acc+bias
// ---------------------------------------------------------------------------
enum CMode { CM_QK = 0, CM_VT = 1, CM_OUT = 2 };

template<int MODE>
__global__ __launch_bounds__(256) void gemm_nt(const bf16* __restrict__ A,
                                               const bf16* __restrict__ Bm,
                                               const float* __restrict__ bias,
                                               void* __restrict__ Cout,
                                               float scale) {
  constexpr int K = 1024;
  constexpr int BK = 64;
  __shared__ __align__(16) bf16 As[128 * BK];
  __shared__ __align__(16) bf16 Bs[128 * BK];

  const int tid = threadIdx.x;
  const int bn = blockIdx.x;        // N tile
  const int bm = blockIdx.y;        // M tile
  const int w = tid >> 6, l = tid & 63;
  const int wr = w >> 1, wc = w & 1;
  const int lr = l & 15, lk = l >> 4;

  f32x4 acc[4][4] = {};

  for (int k0 = 0; k0 < K; k0 += BK) {
    // stage A tile (128 rows x 64 k), pre-swizzled source
#pragma unroll
    for (int i = 0; i < 4; ++i) {
      int p = i * 256 + tid;
      int row = p >> 3;
      int so = (p & 7) ^ (row & 7);
      gld_lds16(A + (size_t)(bm * 128 + row) * K + k0 + so * 8, &As[p * 8]);
    }
#pragma unroll
    for (int i = 0; i < 4; ++i) {
      int p = i * 256 + tid;
      int row = p >> 3;
      int so = (p & 7) ^ (row & 7);
      gld_lds16(Bm + (size_t)(bn * 128 + row) * K + k0 + so * 8, &Bs[p * 8]);
    }
    __syncthreads();   // compiler drains vmcnt(0) before barrier

#pragma unroll
    for (int kk = 0; kk < 2; ++kk) {
      bf16x8 af[4], bfr[4];
#pragma unroll
      for (int m = 0; m < 4; ++m) {
        int row = wr * 64 + m * 16 + lr;
        int slot = (kk * 4 + lk) ^ (row & 7);
        af[m] = *reinterpret_cast<const bf16x8*>(&As[row * BK + slot * 8]);
      }
#pragma unroll
      for (int n = 0; n < 4; ++n) {
        int row = wc * 64 + n * 16 + lr;
        int slot = (kk * 4 + lk) ^ (row & 7);
        bfr[n] = *reinterpret_cast<const bf16x8*>(&Bs[row * BK + slot * 8]);
      }
#pragma unroll
      for (int m = 0; m < 4; ++m)
#pragma unroll
        for (int n = 0; n < 4; ++n)
          acc[m][n] = __builtin_amdgcn_mfma_f32_16x16x32_bf16(af[m], bfr[n], acc[m][n], 0, 0, 0);
    }
    __syncthreads();
  }

  // epilogue: D layout col = lane&15, row = (lane>>4)*4 + reg
  const int crow0 = bm * 128 + wr * 64;
  const int ccol0 = bn * 128 + wc * 64;
#pragma unroll
  for (int m = 0; m < 4; ++m) {
#pragma unroll
    for (int n = 0; n < 4; ++n) {
#pragma unroll
      for (int r = 0; r < 4; ++r) {
        const int row = crow0 + m * 16 + lk * 4 + r;
        const int col = ccol0 + n * 16 + lr;
        if constexpr (MODE == CM_QK) {
          float v = (acc[m][n][r] + bias[col]) * scale;
          // (B,H,T,DK): row=(b,t), col=(h,dk)
          size_t idx = (((size_t)(row >> 11) * H_ + (col >> 6)) * T_ + (row & (T_ - 1))) * DK_ + (col & (DK_ - 1));
          ((bf16*)Cout)[idx] = __float2bfloat16(v);
        } else if constexpr (MODE == CM_VT) {
          float v = acc[m][n][r] + bias[row];   // row = output feature
          // (B,H,DK,T): row=(h,dk) feature, col=(b,t)
          size_t idx = (size_t)(col >> 11) * ((size_t)H_ * DK_ * T_) + (size_t)row * T_ + (col & (T_ - 1));
          ((bf16*)Cout)[idx] = __float2bfloat16(v);
        } else {
          float v = acc[m][n][r] + bias[col];
          ((float*)Cout)[(size_t)row * D_ + col] = v;
        }
      }
    }
  }
}

// ---------------------------------------------------------------------------
// Causal flash attention.
// grid (32, 64): x -> q-tile (reversed for load balance), y -> (b*H+h).
// Block: 4 waves; wave w owns q rows [qt*64 + w*16, +16), full DK=64.
// K tile [128 kcol][64 dk] and Vt tile [64 dk][128 kcol] staged via
// global_load_lds with XOR swizzle; P goes through per-wave swizzled LDS.
// ---------------------------------------------------------------------------
__global__ __launch_bounds__(256) void attn_fwd(const bf16* __restrict__ Qh,
                                                const bf16* __restrict__ Kh,
                                                const bf16* __restrict__ Vt,
                                                bf16* __restrict__ ctx) {
  __shared__ __align__(16) bf16 Ks[128 * 64];      // [kcol][dk], 8 slots/row, ^row&7
  __shared__ __align__(16) bf16 Vts[64 * 128];     // [dk][kcol], 16 slots/row, ^row&15
  __shared__ __align__(16) bf16 Ps[4][16 * 128];   // per-wave [qrow][kcol], ^row&15

  const int qt = 31 - blockIdx.x;                  // longest blocks first
  const int bh = blockIdx.y;
  const int tid = threadIdx.x, w = tid >> 6, l = tid & 63;
  const int lr = l & 15, lk = l >> 4;
  const int q0 = qt * 64 + w * 16;

  const bf16* Qb = Qh + (size_t)bh * T_ * DK_;
  const bf16* Kb = Kh + (size_t)bh * T_ * DK_;
  const bf16* Vb = Vt + (size_t)bh * DK_ * T_;

  // Q fragments live in registers (A operand: row = lane&15, k = (lane>>4)*8)
  bf16x8 qf0 = *reinterpret_cast<const bf16x8*>(Qb + (size_t)(q0 + lr) * DK_ + lk * 8);
  bf16x8 qf1 = *reinterpret_cast<const bf16x8*>(Qb + (size_t)(q0 + lr) * DK_ + 32 + lk * 8);

  f32x4 oacc[4] = {};
  float mrow[4], srow[4];
#pragma unroll
  for (int r = 0; r < 4; ++r) { mrow[r] = -1e30f; srow[r] = 0.f; }

  const int nt = (qt >> 1) + 1;
  for (int j = 0; j < nt; ++j) {
    const int k0 = j * 128;
    __syncthreads();   // previous iter's PV reads done before restaging
#pragma unroll
    for (int i = 0; i < 4; ++i) {          // K tile: 1024 x 16B slots
      int p = i * 256 + tid;
      int row = p >> 3;
      int so = (p & 7) ^ (row & 7);
      gld_lds16(Kb + (size_t)(k0 + row) * DK_ + so * 8, &Ks[p * 8]);
    }
#pragma unroll
    for (int i = 0; i < 4; ++i) {          // Vt tile: 1024 x 16B slots
      int p = i * 256 + tid;
      int row = p >> 4;
      int so = (p & 15) ^ (row & 15);
      gld_lds16(Vb + (size_t)row * T_ + k0 + so * 8, &Vts[p * 8]);
    }
    __syncthreads();

    // S = Q K^T  (rows: lk*4+r, cols: n*16+lr)
    f32x4 sacc[8];
#pragma unroll
    for (int n = 0; n < 8; ++n) {
      sacc[n] = f32x4{0.f, 0.f, 0.f, 0.f};
      {
        int row = n * 16 + lr;
        int s0 = (0 * 4 + lk) ^ (row & 7);
        int s1 = (1 * 4 + lk) ^ (row & 7);
        bf16x8 kf0 = *reinterpret_cast<const bf16x8*>(&Ks[row * 64 + s0 * 8]);
        bf16x8 kf1 = *reinterpret_cast<const bf16x8*>(&Ks[row * 64 + s1 * 8]);
        sacc[n] = __builtin_amdgcn_mfma_f32_16x16x32_bf16(qf0, kf0, sacc[n], 0, 0, 0);
        sacc[n] = __builtin_amdgcn_mfma_f32_16x16x32_bf16(qf1, kf1, sacc[n], 0, 0, 0);
      }
    }

    // causal mask + tile row-max
    float tm[4];
#pragma unroll
    for (int r = 0; r < 4; ++r) tm[r] = -1e30f;
#pragma unroll
    for (int n = 0; n < 8; ++n) {
      int colg = k0 + n * 16 + lr;
#pragma unroll
      for (int r = 0; r < 4; ++r) {
        int rowg = q0 + lk * 4 + r;
        float sv = (colg <= rowg) ? sacc[n][r] : -1e30f;
        sacc[n][r] = sv;
        tm[r] = fmaxf(tm[r], sv);
      }
    }
#pragma unroll
    for (int r = 0; r < 4; ++r)
#pragma unroll
      for (int mb = 1; mb < 16; mb <<= 1)
        tm[r] = fmaxf(tm[r], __shfl_xor(tm[r], mb, 64));

    float sc[4], ts[4];
#pragma unroll
    for (int r = 0; r < 4; ++r) {
      float mn = fmaxf(mrow[r], tm[r]);
      sc[r] = __expf(mrow[r] - mn);
      mrow[r] = mn;
      ts[r] = 0.f;
    }

    // P = exp(S - m), write swizzled bf16 to per-wave LDS
#pragma unroll
    for (int n = 0; n < 8; ++n) {
#pragma unroll
      for (int r = 0; r < 4; ++r) {
        float p = __expf(sacc[n][r] - mrow[r]);
        ts[r] += p;
        int row = lk * 4 + r;
        int col = n * 16 + lr;
        int slot = (col >> 3) ^ (row & 15);
        Ps[w][row * 128 + slot * 8 + (col & 7)] = __float2bfloat16(p);
      }
    }
#pragma unroll
    for (int r = 0; r < 4; ++r) {
#pragma unroll
      for (int mb = 1; mb < 16; mb <<= 1)
        ts[r] += __shfl_xor(ts[r], mb, 64);
      srow[r] = srow[r] * sc[r] + ts[r];
    }
#pragma unroll
    for (int n = 0; n < 4; ++n)
#pragma unroll
      for (int r = 0; r < 4; ++r)
        oacc[n][r] *= sc[r];

    __syncthreads();   // Ps visible

    // O += P V  (A = P from Ps, B = V^T from Vts)
    bf16x8 pa[4];
#pragma unroll
    for (int kk = 0; kk < 4; ++kk) {
      int slot = (kk * 4 + lk) ^ (lr & 15);
      pa[kk] = *reinterpret_cast<const bf16x8*>(&Ps[w][lr * 128 + slot * 8]);
    }
#pragma unroll
    for (int n = 0; n < 4; ++n) {
#pragma unroll
      for (int kk = 0; kk < 4; ++kk) {
        int row = n * 16 + lr;
        int slot = (kk * 4 + lk) ^ (row & 15);
        bf16x8 vb = *reinterpret_cast<const bf16x8*>(&Vts[row * 128 + slot * 8]);
        oacc[n] = __builtin_amdgcn_mfma_f32_16x16x32_bf16(pa[kk], vb, oacc[n], 0, 0, 0);
      }
    }
  }

  // normalize + store ctx (B,T,D) bf16
  const int bb = bh >> 4, hh = bh & 15;
#pragma unroll
  for (int n = 0; n < 4; ++n) {
#pragma unroll
    for (int r = 0; r < 4; ++r) {
      float o = oacc[n][r] / srow[r];
      int trow = q0 + lk * 4 + r;
      ctx[((size_t)(bb * T_ + trow)) * D_ + hh * DK_ + n * 16 + lr] = __float2bfloat16(o);
    }
  }
}

// ---------------------------------------------------------------------------
// launch
// ---------------------------------------------------------------------------
extern "C" void kernel_launch(void* const* d_in, const int* in_sizes, int n_in,
                              void* d_out, int out_size, void* d_ws, size_t ws_size,
                              hipStream_t stream) {
  const float* q  = (const float*)d_in[0];
  const float* k  = (const float*)d_in[1];
  const float* v  = (const float*)d_in[2];
  const float* Wq = (const float*)d_in[3];
  const float* Wk = (const float*)d_in[4];
  const float* Wv = (const float*)d_in[5];
  const float* Wo = (const float*)d_in[6];
  const float* bq = (const float*)d_in[7];
  const float* bk = (const float*)d_in[8];
  const float* bv = (const float*)d_in[9];
  const float* bo = (const float*)d_in[10];

  constexpr size_t E_IN = (size_t)M_ * D_;   // 8388608 elems
  constexpr size_t E_W  = (size_t)D_ * D_;   // 1048576 elems
  char* ws = (char*)d_ws;
  size_t off = 0;
  bf16* qb  = (bf16*)(ws + off); off += E_IN * 2;
  bf16* kb  = (bf16*)(ws + off); off += E_IN * 2;
  bf16* vb  = (bf16*)(ws + off); off += E_IN * 2;
  bf16* Wqb = (bf16*)(ws + off); off += E_W * 2;
  bf16* Wkb = (bf16*)(ws + off); off += E_W * 2;
  bf16* Wvb = (bf16*)(ws + off); off += E_W * 2;
  bf16* Wob = (bf16*)(ws + off); off += E_W * 2;
  bf16* Qh  = (bf16*)(ws + off); off += E_IN * 2;
  bf16* Kh  = (bf16*)(ws + off); off += E_IN * 2;
  bf16* Vtw = (bf16*)(ws + off); off += E_IN * 2;
  bf16* ctx = (bf16*)(ws + off); off += E_IN * 2;

  // fp32 -> bf16 converts
  cvt_bf16<<<dim3(E_IN / 4 / 256), dim3(256), 0, stream>>>(q, qb, (int)(E_IN / 4));
  cvt_bf16<<<dim3(E_IN / 4 / 256), dim3(256), 0, stream>>>(k, kb, (int)(E_IN / 4));
  cvt_bf16<<<dim3(E_IN / 4 / 256), dim3(256), 0, stream>>>(v, vb, (int)(E_IN / 4));
  cvt_bf16<<<dim3(E_W / 4 / 256), dim3(256), 0, stream>>>(Wq, Wqb, (int)(E_W / 4));
  cvt_bf16<<<dim3(E_W / 4 / 256), dim3(256), 0, stream>>>(Wk, Wkb, (int)(E_W / 4));
  cvt_bf16<<<dim3(E_W / 4 / 256), dim3(256), 0, stream>>>(Wv, Wvb, (int)(E_W / 4));
  cvt_bf16<<<dim3(E_W / 4 / 256), dim3(256), 0, stream>>>(Wo, Wob, (int)(E_W / 4));

  // projections: Q (scaled by 1/sqrt(DK)), K, and V in transposed layout
  dim3 g_qk(D_ / 128, M_ / 128);   // (8, 64)
  gemm_nt<CM_QK><<<g_qk, dim3(256), 0, stream>>>(qb, Wqb, bq, Qh, 0.125f);
  gemm_nt<CM_QK><<<g_qk, dim3(256), 0, stream>>>(kb, Wkb, bk, Kh, 1.0f);
  dim3 g_vt(M_ / 128, D_ / 128);   // (64, 8): A = Wv (M=1024), B = v (N=8192)
  gemm_nt<CM_VT><<<g_vt, dim3(256), 0, stream>>>(Wvb, vb, bv, Vtw, 1.0f);

  // causal attention -> ctx (B,T,D) bf16
  attn_fwd<<<dim3(32, 64), dim3(256), 0, stream>>>(Qh, Kh, Vtw, ctx);

  // output projection -> fp32 d_out
  gemm_nt<CM_OUT><<<g_qk, dim3(256), 0, stream>>>(ctx, Wob, bo, d_out, 1.0f);
}